// Round 2
// baseline (468.837 us; speedup 1.0000x reference)
//
#include <hip/hip_runtime.h>

typedef unsigned short ushort_t;
typedef unsigned int uint_t;
typedef __attribute__((ext_vector_type(8))) short bf16x8;
typedef __attribute__((ext_vector_type(8))) unsigned short us8;
typedef __attribute__((ext_vector_type(4))) float f32x4;
typedef __attribute__((ext_vector_type(4))) unsigned short us4;

#define NN 8192
#define FF 128

__device__ __forceinline__ float bf2f(ushort_t u) {
    union { unsigned u; float f; } v;
    v.u = ((unsigned)u) << 16;
    return v.f;
}

__device__ __forceinline__ ushort_t f2bf(float f) {
    union { float f; unsigned u; } v;
    v.f = f;
    unsigned r = (v.u + 0x7fffu + ((v.u >> 16) & 1u)) >> 16;  // RNE
    return (ushort_t)r;
}

// ---- Kernel 1: d[row] = rsqrt(rowsum f32)  +  Abf[row] = bf16(A[row]) ----
// Detection folded in; block 0 also zeroes the 64 per-rowTile completion
// counters used by the fused spmm+reduce kernel (stream order prep->spmm
// guarantees visibility; re-zeroed every launch so graph replay is safe).
// LLC policy: A fp32 loads NONTEMPORAL (stream); Abf stores NORMAL so the
// 128 MB bf16 copy stays Infinity-Cache-resident for spmm.
__global__ __launch_bounds__(256) void gcn_prep(const void* __restrict__ Av,
                                                const void* __restrict__ Xv,
                                                const void* __restrict__ Wv,
                                                int* __restrict__ flags,
                                                float* __restrict__ d,
                                                ushort_t* __restrict__ Abf,
                                                int haveAbf) {
    int row = blockIdx.x;
    int tid = threadIdx.x;
    __shared__ int aIsBf;
    __shared__ float red[4];

    if (tid < 64) {
        // A dtype probe: indices valid under both interpretations (<32M uints)
        uint_t u = ((const uint_t*)Av)[(size_t)tid * 499999u];
        float f = bf2f((ushort_t)(u & 0xFFFFu));
        unsigned long long m = __ballot(f >= 0.f && f < 1.f);
        if (tid == 0) aIsBf = (__popcll(m) >= 48) ? 1 : 0;
    } else if (row == 0 && tid < 128) {
        int lane = tid - 64;
        uint_t u = ((const uint_t*)Xv)[(size_t)lane * 8000u];
        float f = bf2f((ushort_t)(u & 0xFFFFu));
        float a = fabsf(f);
        unsigned long long m = __ballot(a < 8.f && (f == 0.f || a > 9.5e-7f));
        if (lane == 0) flags[1] = (__popcll(m) >= 48) ? 1 : 0;
    } else if (row == 0 && tid < 192) {
        int lane = tid - 128;
        uint_t u = ((const uint_t*)Wv)[(size_t)lane * 126u];
        float f = bf2f((ushort_t)(u & 0xFFFFu));
        float a = fabsf(f);
        unsigned long long m = __ballot(a < 8.f && (f == 0.f || a > 9.5e-7f));
        if (lane == 0) flags[2] = (__popcll(m) >= 48) ? 1 : 0;
    } else if (row == 0) {
        flags[128 + (tid - 192)] = 0;  // zero 64 rowTile completion counters
    }
    __syncthreads();
    int isbf = aIsBf;
    if (row == 0 && tid == 0) flags[0] = isbf;

    float s = 0.f;
    if (isbf) {  // already bf16: rowsum only, spmm reads A directly (LLC keeps it)
        const bf16x8* a8 = (const bf16x8*)((const ushort_t*)Av + (size_t)row * NN);
        #pragma unroll
        for (int i = 0; i < 4; i++) {
            bf16x8 v = a8[tid + i * 256];
            #pragma unroll
            for (int j = 0; j < 8; j++) s += bf2f((ushort_t)v[j]);
        }
    } else {
        const f32x4* a4 = (const f32x4*)((const float*)Av + (size_t)row * NN);
        us4* ob = (us4*)(Abf + (size_t)row * NN);
        #pragma unroll
        for (int i = 0; i < 8; i++) {
            f32x4 v = __builtin_nontemporal_load(a4 + tid + i * 256);  // stream A past LLC
            s += v[0] + v[1] + v[2] + v[3];
            if (haveAbf) {
                us4 o;
                o[0] = f2bf(v[0]); o[1] = f2bf(v[1]); o[2] = f2bf(v[2]); o[3] = f2bf(v[3]);
                ob[tid + i * 256] = o;  // NORMAL store: keep Abf LLC-resident for spmm
            }
        }
    }
    #pragma unroll
    for (int off = 32; off > 0; off >>= 1) s += __shfl_down(s, off, 64);
    if ((tid & 63) == 0) red[tid >> 6] = s;
    __syncthreads();
    if (tid == 0) d[row] = rsqrtf(red[0] + red[1] + red[2] + red[3]);
}

// ---------------- Kernel 2: Yt[n][k] = bf16( d[k] * (X @ W)[k][n] ) ----------------
__global__ __launch_bounds__(256) void gcn_xw(const void* __restrict__ Xv,
                                              const void* __restrict__ Wv,
                                              const int* __restrict__ flags,
                                              const float* __restrict__ dv,
                                              ushort_t* __restrict__ Yt) {
    __shared__ ushort_t Ws[128 * 132];
    __shared__ ushort_t Xs[32 * 128];
    __shared__ float ds[32];
    int t = threadIdx.x;
    int k0 = blockIdx.x * 32;
    if (flags[2]) {
        const ushort_t* Wm = (const ushort_t*)Wv;
        for (int i = t; i < 128 * 128; i += 256) {
            int f = i >> 7, n = i & 127;
            Ws[n * 132 + f] = Wm[i];
        }
    } else {
        const float* Wm = (const float*)Wv;
        for (int i = t; i < 128 * 128; i += 256) {
            int f = i >> 7, n = i & 127;
            Ws[n * 132 + f] = f2bf(Wm[i]);
        }
    }
    if (flags[1]) {
        const ushort_t* X = (const ushort_t*)Xv;
        for (int i = t; i < 32 * 128; i += 256) Xs[i] = X[(size_t)k0 * FF + i];
    } else {
        const float* X = (const float*)Xv;
        for (int i = t; i < 32 * 128; i += 256) Xs[i] = f2bf(X[(size_t)k0 * FF + i]);
    }
    if (t < 32) ds[t] = dv[k0 + t];
    __syncthreads();

    int n = t & 127, kb = (t >> 7) * 16;
    float acc[16];
    #pragma unroll
    for (int j = 0; j < 16; j++) acc[j] = 0.f;
    for (int f = 0; f < 128; f += 4) {
        us4 wq = *(const us4*)&Ws[n * 132 + f];
        float w0 = bf2f(wq[0]), w1 = bf2f(wq[1]), w2 = bf2f(wq[2]), w3 = bf2f(wq[3]);
        #pragma unroll
        for (int j = 0; j < 16; j++) {
            us4 xq = *(const us4*)&Xs[(kb + j) * 128 + f];
            acc[j] += bf2f(xq[0]) * w0 + bf2f(xq[1]) * w1 + bf2f(xq[2]) * w2 + bf2f(xq[3]) * w3;
        }
    }
    // Each thread holds 16 CONSECUTIVE k for one row n -> pack into 2x us8
    us8 o0, o1;
    #pragma unroll
    for (int j = 0; j < 8; j++) o0[j] = f2bf(ds[kb + j] * acc[j]);
    #pragma unroll
    for (int j = 0; j < 8; j++) o1[j] = f2bf(ds[kb + 8 + j] * acc[8 + j]);
    *(us8*)&Yt[(size_t)n * NN + (k0 + kb)] = o0;
    *(us8*)&Yt[(size_t)n * NN + (k0 + kb + 8)] = o1;
}

// -------- Kernel 3: partial Z = Abf @ Y  (split-K, bf16 MFMA) + FUSED reduce --------
// B-tile (128n x 64k) staged in LDS once per block, XOR-swizzled 16B chunks;
// A direct global->reg; next-step A/B prefetched in regs.
// NEW: last split block per rowTile (device-scope counter) reduces the 8 P
// slices (L2-hot) and applies d[row]*(.)+b, ReLU -> out. Removes the separate
// gcn_reduce dispatch and its cooled-memory P re-read.
__global__ __launch_bounds__(256, 2) void gcn_spmm(const void* __restrict__ Av,
                                                   int* __restrict__ flags,
                                                   const ushort_t* __restrict__ Abf,
                                                   const ushort_t* __restrict__ Yt,
                                                   float* __restrict__ P,
                                                   const float* __restrict__ d,
                                                   const void* __restrict__ bv,
                                                   void* __restrict__ out,
                                                   int nsplit) {
    __shared__ ushort_t Bs[128 * 64];  // [n][chunk] 16 KiB, chunk c of row n holds logical chunk c^(n&7)
    const int chunk = NN / nsplit;
    const int steps = chunk / 64;
    int bid = blockIdx.x;
    int rowTile = bid & 63;
    int sp = bid >> 6;
    int lane = threadIdx.x & 63;
    int w = threadIdx.x >> 6;
    int m15 = lane & 15, quad = lane >> 4;
    int row0 = rowTile * 128 + w * 32;
    const int kBeg = sp * chunk;
    const int kq = quad * 8;

    const ushort_t* Ab = flags[0] ? (const ushort_t*)Av : Abf;
    const ushort_t* pa0 = Ab + (size_t)(row0 + m15) * NN;
    const ushort_t* pa1 = Ab + (size_t)(row0 + 16 + m15) * NN;

    // B staging: wave w covers issues e = w*4+i; lane handles row rB = e*8 + (lane>>3),
    // fetching global chunk (lane&7)^(rB&7) into physical chunk lane&7.
    const ushort_t* gB[4];
    ushort_t* lB[4];
    #pragma unroll
    for (int i = 0; i < 4; i++) {
        int e = w * 4 + i;
        int r = e * 8 + (lane >> 3);
        int cs = (lane & 7) ^ (r & 7);
        gB[i] = Yt + (size_t)r * NN + cs * 8;
        lB[i] = Bs + e * 512 + lane * 8;
    }

    f32x4 acc[2][8];
    #pragma unroll
    for (int g = 0; g < 2; g++)
        #pragma unroll
        for (int c = 0; c < 8; c++) acc[g][c] = (f32x4)(0.f);

    bf16x8 a[2][2], an[2][2];
    us8 bvv[4], bvn[4];
    #pragma unroll
    for (int h = 0; h < 2; h++) {
        a[0][h] = *(const bf16x8*)(pa0 + kBeg + h * 32 + kq);
        a[1][h] = *(const bf16x8*)(pa1 + kBeg + h * 32 + kq);
    }
    #pragma unroll
    for (int i = 0; i < 4; i++) bvv[i] = *(const us8*)(gB[i] + kBeg);

    for (int st = 0; st < steps; st++) {
        __syncthreads();  // previous compute done reading Bs
        #pragma unroll
        for (int i = 0; i < 4; i++) *(us8*)lB[i] = bvv[i];
        __syncthreads();  // Bs ready
        int kn = (st + 1 < steps) ? kBeg + (st + 1) * 64 : kBeg;  // wrap harmless
        #pragma unroll
        for (int i = 0; i < 4; i++) bvn[i] = *(const us8*)(gB[i] + kn);
        #pragma unroll
        for (int h = 0; h < 2; h++) {
            an[0][h] = *(const bf16x8*)(pa0 + kn + h * 32 + kq);
            an[1][h] = *(const bf16x8*)(pa1 + kn + h * 32 + kq);
        }
        #pragma unroll
        for (int h = 0; h < 2; h++) {
            bf16x8 bf[8];
            #pragma unroll
            for (int c = 0; c < 8; c++) {
                int n = c * 16 + m15;
                int pc = (h * 4 + quad) ^ (n & 7);
                bf[c] = *(const bf16x8*)(Bs + n * 64 + pc * 8);
            }
            #pragma unroll
            for (int c = 0; c < 8; c++) {
                acc[0][c] = __builtin_amdgcn_mfma_f32_16x16x32_bf16(a[0][h], bf[c], acc[0][c], 0, 0, 0);
                acc[1][c] = __builtin_amdgcn_mfma_f32_16x16x32_bf16(a[1][h], bf[c], acc[1][c], 0, 0, 0);
            }
        }
        #pragma unroll
        for (int h = 0; h < 2; h++) {
            a[0][h] = an[0][h];
            a[1][h] = an[1][h];
        }
        #pragma unroll
        for (int i = 0; i < 4; i++) bvv[i] = bvn[i];
    }

    // C/D layout: col = lane&15, row = quad*4 + reg  [verified m89/m91]
    float* Pp = P + (size_t)sp * (NN * 128);
    #pragma unroll
    for (int g = 0; g < 2; g++)
        #pragma unroll
        for (int c = 0; c < 8; c++)
            #pragma unroll
            for (int r = 0; r < 4; r++) {
                int row = row0 + g * 16 + quad * 4 + r;
                int n = c * 16 + m15;
                Pp[(size_t)row * 128 + n] = acc[g][c][r];
            }

    // ---- completion counter: last block for this rowTile does the reduce ----
    __syncthreads();  // all waves' P stores executed (barrier drains vmcnt -> L2)
    __shared__ int amLast;
    if (threadIdx.x == 0) {
        __threadfence();  // release: flush this XCD's L2 (P slice device-visible)
        int old = atomicAdd(&flags[128 + rowTile], 1);
        amLast = (old == nsplit - 1);
    }
    __syncthreads();
    if (!amLast) return;
    __threadfence();  // acquire: invalidate local caches (other XCDs' P slices)

    const size_t tileOff = (size_t)rowTile * 128 * 128;  // f32 elems
    int t = threadIdx.x;
    int isW = flags[2], isX = flags[1];
    #pragma unroll
    for (int i = 0; i < 16; i++) {
        int li = i * 256 + t;  // f32x4 index within tile (0..4095), coalesced
        f32x4 s = *(const f32x4*)(P + tileOff + (size_t)li * 4);
        for (int si = 1; si < nsplit; si++)
            s += *(const f32x4*)(P + (size_t)si * (NN * 128) + tileOff + (size_t)li * 4);
        int rowl = li >> 5;
        int n0 = (li & 31) * 4;
        float dvv = d[rowTile * 128 + rowl];
        f32x4 r;
        #pragma unroll
        for (int j = 0; j < 4; j++) {
            float bvj = isW ? bf2f(((const ushort_t*)bv)[n0 + j])
                            : ((const float*)bv)[n0 + j];
            float x = dvv * s[j] + bvj;
            r[j] = x > 0.f ? x : 0.f;
        }
        size_t oidx = (size_t)(rowTile * 128 + rowl) * 128 + n0;
        if (isX) {
            us4 o;
            #pragma unroll
            for (int j = 0; j < 4; j++) o[j] = f2bf(r[j]);
            *(us4*)((ushort_t*)out + oidx) = o;
        } else {
            *(f32x4*)((float*)out + oidx) = r;
        }
    }
}

extern "C" void kernel_launch(void* const* d_in, const int* in_sizes, int n_in,
                              void* d_out, int out_size, void* d_ws, size_t ws_size,
                              hipStream_t stream) {
    const void* A = d_in[0];  // [8192][8192]
    const void* X = d_in[1];  // [8192][128]
    const void* W = d_in[2];  // [128][128]
    const void* b = d_in[3];  // [128]

    char* wsb = (char*)d_ws;
    int* flags = (int*)wsb;                                   // 1 KB (incl. 64 counters at +128 ints)
    float* d_deg = (float*)(wsb + 1024);                      // 32 KB
    ushort_t* Yt = (ushort_t*)(wsb + 1024 + 32768);           // 2 MB
    const size_t pOff = 1024 + 32768 + 2097152;               // 2130944
    float* P = (float*)(wsb + pOff);                          // nsplit * 4 MB

    int nsplit = 1;
    if (pOff + 8ull * 4194304 <= ws_size) nsplit = 8;
    else if (pOff + 4ull * 4194304 <= ws_size) nsplit = 4;
    else if (pOff + 2ull * 4194304 <= ws_size) nsplit = 2;

    const size_t abfOff = pOff + (size_t)nsplit * 4194304;
    int haveAbf = (abfOff + 134217728ull <= ws_size) ? 1 : 0;  // 128 MiB bf16 copy of A
    ushort_t* Abf = (ushort_t*)(wsb + abfOff);

    gcn_prep<<<NN, 256, 0, stream>>>(A, X, W, flags, d_deg, Abf, haveAbf);
    gcn_xw<<<NN / 32, 256, 0, stream>>>(X, W, flags, d_deg, Yt);
    if (haveAbf) {
        gcn_spmm<<<64 * nsplit, 256, 0, stream>>>(A, flags, Abf, Yt, P, d_deg, b, d_out, nsplit);
    } else {
        // only correct when input already bf16; in practice ws is large and haveAbf=1
        gcn_spmm<<<64 * nsplit, 256, 0, stream>>>(A, flags, (const ushort_t*)A, Yt, P, d_deg, b, d_out, nsplit);
    }
}

// Round 3
// 414.914 us; speedup vs baseline: 1.1300x; 1.1300x over previous
//
#include <hip/hip_runtime.h>

typedef unsigned short ushort_t;
typedef unsigned int uint_t;
typedef __attribute__((ext_vector_type(8))) short bf16x8;
typedef __attribute__((ext_vector_type(8))) unsigned short us8;
typedef __attribute__((ext_vector_type(4))) float f32x4;
typedef __attribute__((ext_vector_type(4))) unsigned short us4;

#define NN 8192
#define FF 128

__device__ __forceinline__ float bf2f(ushort_t u) {
    union { unsigned u; float f; } v;
    v.u = ((unsigned)u) << 16;
    return v.f;
}

__device__ __forceinline__ ushort_t f2bf(float f) {
    union { float f; unsigned u; } v;
    v.f = f;
    unsigned r = (v.u + 0x7fffu + ((v.u >> 16) & 1u)) >> 16;  // RNE
    return (ushort_t)r;
}

// ---- Kernel 1: d[row] = rsqrt(rowsum f32)  +  Abf[row] = bf16(A[row]) ----
// Detection folded in: every block self-detects A dtype from the same 64
// sample locations (L2-hot after first blocks); block 0 also writes flags[0..2]
// for the downstream kernels.
// LLC policy: A fp32 loads NONTEMPORAL (stream); Abf stores NORMAL so the
// 128 MB bf16 copy stays Infinity-Cache-resident for spmm.
__global__ __launch_bounds__(256) void gcn_prep(const void* __restrict__ Av,
                                                const void* __restrict__ Xv,
                                                const void* __restrict__ Wv,
                                                int* __restrict__ flags,
                                                float* __restrict__ d,
                                                ushort_t* __restrict__ Abf,
                                                int haveAbf) {
    int row = blockIdx.x;
    int tid = threadIdx.x;
    __shared__ int aIsBf;
    __shared__ float red[4];

    if (tid < 64) {
        // A dtype probe: indices valid under both interpretations (<32M uints)
        uint_t u = ((const uint_t*)Av)[(size_t)tid * 499999u];
        float f = bf2f((ushort_t)(u & 0xFFFFu));
        unsigned long long m = __ballot(f >= 0.f && f < 1.f);
        if (tid == 0) aIsBf = (__popcll(m) >= 48) ? 1 : 0;
    } else if (row == 0 && tid < 128) {
        int lane = tid - 64;
        uint_t u = ((const uint_t*)Xv)[(size_t)lane * 8000u];
        float f = bf2f((ushort_t)(u & 0xFFFFu));
        float a = fabsf(f);
        unsigned long long m = __ballot(a < 8.f && (f == 0.f || a > 9.5e-7f));
        if (lane == 0) flags[1] = (__popcll(m) >= 48) ? 1 : 0;
    } else if (row == 0 && tid < 192) {
        int lane = tid - 128;
        uint_t u = ((const uint_t*)Wv)[(size_t)lane * 126u];
        float f = bf2f((ushort_t)(u & 0xFFFFu));
        float a = fabsf(f);
        unsigned long long m = __ballot(a < 8.f && (f == 0.f || a > 9.5e-7f));
        if (lane == 0) flags[2] = (__popcll(m) >= 48) ? 1 : 0;
    }
    __syncthreads();
    int isbf = aIsBf;
    if (row == 0 && tid == 0) flags[0] = isbf;

    float s = 0.f;
    if (isbf) {  // already bf16: rowsum only, spmm reads A directly (LLC keeps it)
        const bf16x8* a8 = (const bf16x8*)((const ushort_t*)Av + (size_t)row * NN);
        #pragma unroll
        for (int i = 0; i < 4; i++) {
            bf16x8 v = a8[tid + i * 256];
            #pragma unroll
            for (int j = 0; j < 8; j++) s += bf2f((ushort_t)v[j]);
        }
    } else {
        const f32x4* a4 = (const f32x4*)((const float*)Av + (size_t)row * NN);
        us4* ob = (us4*)(Abf + (size_t)row * NN);
        #pragma unroll
        for (int i = 0; i < 8; i++) {
            f32x4 v = __builtin_nontemporal_load(a4 + tid + i * 256);  // stream A past LLC
            s += v[0] + v[1] + v[2] + v[3];
            if (haveAbf) {
                us4 o;
                o[0] = f2bf(v[0]); o[1] = f2bf(v[1]); o[2] = f2bf(v[2]); o[3] = f2bf(v[3]);
                ob[tid + i * 256] = o;  // NORMAL store: keep Abf LLC-resident for spmm
            }
        }
    }
    #pragma unroll
    for (int off = 32; off > 0; off >>= 1) s += __shfl_down(s, off, 64);
    if ((tid & 63) == 0) red[tid >> 6] = s;
    __syncthreads();
    if (tid == 0) d[row] = rsqrtf(red[0] + red[1] + red[2] + red[3]);
}

// ---------------- Kernel 2: Yt[n][k] = bf16( d[k] * (X @ W)[k][n] ) ----------------
__global__ __launch_bounds__(256) void gcn_xw(const void* __restrict__ Xv,
                                              const void* __restrict__ Wv,
                                              const int* __restrict__ flags,
                                              const float* __restrict__ dv,
                                              ushort_t* __restrict__ Yt) {
    __shared__ ushort_t Ws[128 * 132];
    __shared__ ushort_t Xs[32 * 128];
    __shared__ float ds[32];
    int t = threadIdx.x;
    int k0 = blockIdx.x * 32;
    if (flags[2]) {
        const ushort_t* Wm = (const ushort_t*)Wv;
        for (int i = t; i < 128 * 128; i += 256) {
            int f = i >> 7, n = i & 127;
            Ws[n * 132 + f] = Wm[i];
        }
    } else {
        const float* Wm = (const float*)Wv;
        for (int i = t; i < 128 * 128; i += 256) {
            int f = i >> 7, n = i & 127;
            Ws[n * 132 + f] = f2bf(Wm[i]);
        }
    }
    if (flags[1]) {
        const ushort_t* X = (const ushort_t*)Xv;
        for (int i = t; i < 32 * 128; i += 256) Xs[i] = X[(size_t)k0 * FF + i];
    } else {
        const float* X = (const float*)Xv;
        for (int i = t; i < 32 * 128; i += 256) Xs[i] = f2bf(X[(size_t)k0 * FF + i]);
    }
    if (t < 32) ds[t] = dv[k0 + t];
    __syncthreads();

    int n = t & 127, kb = (t >> 7) * 16;
    float acc[16];
    #pragma unroll
    for (int j = 0; j < 16; j++) acc[j] = 0.f;
    for (int f = 0; f < 128; f += 4) {
        us4 wq = *(const us4*)&Ws[n * 132 + f];
        float w0 = bf2f(wq[0]), w1 = bf2f(wq[1]), w2 = bf2f(wq[2]), w3 = bf2f(wq[3]);
        #pragma unroll
        for (int j = 0; j < 16; j++) {
            us4 xq = *(const us4*)&Xs[(kb + j) * 128 + f];
            acc[j] += bf2f(xq[0]) * w0 + bf2f(xq[1]) * w1 + bf2f(xq[2]) * w2 + bf2f(xq[3]) * w3;
        }
    }
    // Each thread holds 16 CONSECUTIVE k for one row n -> pack into 2x us8
    us8 o0, o1;
    #pragma unroll
    for (int j = 0; j < 8; j++) o0[j] = f2bf(ds[kb + j] * acc[j]);
    #pragma unroll
    for (int j = 0; j < 8; j++) o1[j] = f2bf(ds[kb + 8 + j] * acc[8 + j]);
    *(us8*)&Yt[(size_t)n * NN + (k0 + kb)] = o0;
    *(us8*)&Yt[(size_t)n * NN + (k0 + kb + 8)] = o1;
}

// -------- Kernel 3: partial Z = Abf @ Y  (split-K, bf16 MFMA) --------
// B-tile (128n x 64k) staged in LDS once per block, XOR-swizzled 16B chunks;
// A direct global->reg; next-step A/B prefetched in regs.
// NEW (r3): DOUBLE-BUFFERED Bs + single barrier per K-step. The ds_write of
// the next tile lands in the idle buffer AFTER the MFMA cluster (vmcnt wait
// covered by compute); one barrier guards the swap. Was: sync-write-sync.
__global__ __launch_bounds__(256, 2) void gcn_spmm(const void* __restrict__ Av,
                                                   const int* __restrict__ flags,
                                                   const ushort_t* __restrict__ Abf,
                                                   const ushort_t* __restrict__ Yt,
                                                   float* __restrict__ P, int nsplit) {
    __shared__ ushort_t Bs[2][128 * 64];  // 2 x 16 KiB; chunk c of row n holds logical chunk c^(n&7)
    const int chunk = NN / nsplit;
    const int steps = chunk / 64;
    int bid = blockIdx.x;
    int rowTile = bid & 63;
    int sp = bid >> 6;
    int lane = threadIdx.x & 63;
    int w = threadIdx.x >> 6;
    int m15 = lane & 15, quad = lane >> 4;
    int row0 = rowTile * 128 + w * 32;
    const int kBeg = sp * chunk;
    const int kq = quad * 8;

    const ushort_t* Ab = flags[0] ? (const ushort_t*)Av : Abf;
    const ushort_t* pa0 = Ab + (size_t)(row0 + m15) * NN;
    const ushort_t* pa1 = Ab + (size_t)(row0 + 16 + m15) * NN;

    // B staging: wave w covers issues e = w*4+i; lane handles row rB = e*8 + (lane>>3),
    // fetching global chunk (lane&7)^(rB&7) into physical chunk lane&7.
    const ushort_t* gB[4];
    ushort_t* lB[4];  // destination in buffer 0; add buf*8192 elems for buffer 1
    #pragma unroll
    for (int i = 0; i < 4; i++) {
        int e = w * 4 + i;
        int r = e * 8 + (lane >> 3);
        int cs = (lane & 7) ^ (r & 7);
        gB[i] = Yt + (size_t)r * NN + cs * 8;
        lB[i] = &Bs[0][0] + e * 512 + lane * 8;
    }

    f32x4 acc[2][8];
    #pragma unroll
    for (int g = 0; g < 2; g++)
        #pragma unroll
        for (int c = 0; c < 8; c++) acc[g][c] = (f32x4)(0.f);

    bf16x8 a[2][2], an[2][2];
    us8 bvv[4], bvn[4];
    #pragma unroll
    for (int h = 0; h < 2; h++) {
        a[0][h] = *(const bf16x8*)(pa0 + kBeg + h * 32 + kq);
        a[1][h] = *(const bf16x8*)(pa1 + kBeg + h * 32 + kq);
    }
    #pragma unroll
    for (int i = 0; i < 4; i++) bvv[i] = *(const us8*)(gB[i] + kBeg);
    // prologue: fill buffer 0
    #pragma unroll
    for (int i = 0; i < 4; i++) *(us8*)lB[i] = bvv[i];
    __syncthreads();

    int cur = 0;
    for (int st = 0; st < steps; st++) {
        int kn = (st + 1 < steps) ? kBeg + (st + 1) * 64 : kBeg;  // wrap harmless
        #pragma unroll
        for (int i = 0; i < 4; i++) bvn[i] = *(const us8*)(gB[i] + kn);
        #pragma unroll
        for (int h = 0; h < 2; h++) {
            an[0][h] = *(const bf16x8*)(pa0 + kn + h * 32 + kq);
            an[1][h] = *(const bf16x8*)(pa1 + kn + h * 32 + kq);
        }
        const ushort_t* Bc = &Bs[0][0] + cur * 8192;
        #pragma unroll
        for (int h = 0; h < 2; h++) {
            bf16x8 bf[8];
            #pragma unroll
            for (int c = 0; c < 8; c++) {
                int n = c * 16 + m15;
                int pc = (h * 4 + quad) ^ (n & 7);
                bf[c] = *(const bf16x8*)(Bc + n * 64 + pc * 8);
            }
            #pragma unroll
            for (int c = 0; c < 8; c++) {
                acc[0][c] = __builtin_amdgcn_mfma_f32_16x16x32_bf16(a[0][h], bf[c], acc[0][c], 0, 0, 0);
                acc[1][c] = __builtin_amdgcn_mfma_f32_16x16x32_bf16(a[1][h], bf[c], acc[1][c], 0, 0, 0);
            }
        }
        // stage next tile into the idle buffer (vmcnt wait covered by the MFMAs above)
        #pragma unroll
        for (int i = 0; i < 4; i++) *(us8*)(lB[i] + (cur ^ 1) * 8192) = bvn[i];
        __syncthreads();  // single barrier: next tile ready, safe to swap
        #pragma unroll
        for (int h = 0; h < 2; h++) {
            a[0][h] = an[0][h];
            a[1][h] = an[1][h];
        }
        cur ^= 1;
    }

    // C/D layout: col = lane&15, row = quad*4 + reg  [verified m89/m91]
    float* Pp = P + (size_t)sp * (NN * 128);
    #pragma unroll
    for (int g = 0; g < 2; g++)
        #pragma unroll
        for (int c = 0; c < 8; c++)
            #pragma unroll
            for (int r = 0; r < 4; r++) {
                int row = row0 + g * 16 + quad * 4 + r;
                int n = c * 16 + m15;
                Pp[(size_t)row * 128 + n] = acc[g][c][r];
            }
}

// ---------------- Kernel 4: out = relu(d[i] * sum_s P[s] + b) ----------------
__global__ __launch_bounds__(256) void gcn_reduce(const float* __restrict__ P,
                                                  const float* __restrict__ d,
                                                  const void* __restrict__ bv,
                                                  const int* __restrict__ flags,
                                                  void* __restrict__ out, int nsplit) {
    int t = blockIdx.x * 256 + threadIdx.x;
    if (t >= NN * 128 / 4) return;
    int row = t >> 5;
    int nq = t & 31;
    f32x4 s = *(const f32x4*)(P + (size_t)t * 4);
    for (int si = 1; si < nsplit; si++)
        s += *(const f32x4*)(P + (size_t)si * (NN * 128) + (size_t)t * 4);
    float dv = d[row];
    f32x4 r;
    #pragma unroll
    for (int j = 0; j < 4; j++) {
        float bvj = flags[2] ? bf2f(((const ushort_t*)bv)[nq * 4 + j])
                             : ((const float*)bv)[nq * 4 + j];
        float x = dv * s[j] + bvj;
        r[j] = x > 0.f ? x : 0.f;
    }
    if (flags[1]) {
        us4 o;
        #pragma unroll
        for (int j = 0; j < 4; j++) o[j] = f2bf(r[j]);
        *(us4*)((ushort_t*)out + (size_t)t * 4) = o;
    } else {
        *(f32x4*)((float*)out + (size_t)t * 4) = r;
    }
}

extern "C" void kernel_launch(void* const* d_in, const int* in_sizes, int n_in,
                              void* d_out, int out_size, void* d_ws, size_t ws_size,
                              hipStream_t stream) {
    const void* A = d_in[0];  // [8192][8192]
    const void* X = d_in[1];  // [8192][128]
    const void* W = d_in[2];  // [128][128]
    const void* b = d_in[3];  // [128]

    char* wsb = (char*)d_ws;
    int* flags = (int*)wsb;                                   // 1 KB
    float* d_deg = (float*)(wsb + 1024);                      // 32 KB
    ushort_t* Yt = (ushort_t*)(wsb + 1024 + 32768);           // 2 MB
    const size_t pOff = 1024 + 32768 + 2097152;               // 2130944
    float* P = (float*)(wsb + pOff);                          // nsplit * 4 MB

    int nsplit = 1;
    if (pOff + 8ull * 4194304 <= ws_size) nsplit = 8;
    else if (pOff + 4ull * 4194304 <= ws_size) nsplit = 4;
    else if (pOff + 2ull * 4194304 <= ws_size) nsplit = 2;

    const size_t abfOff = pOff + (size_t)nsplit * 4194304;
    int haveAbf = (abfOff + 134217728ull <= ws_size) ? 1 : 0;  // 128 MiB bf16 copy of A
    ushort_t* Abf = (ushort_t*)(wsb + abfOff);

    gcn_prep<<<NN, 256, 0, stream>>>(A, X, W, flags, d_deg, Abf, haveAbf);
    gcn_xw<<<NN / 32, 256, 0, stream>>>(X, W, flags, d_deg, Yt);
    if (haveAbf) {
        gcn_spmm<<<64 * nsplit, 256, 0, stream>>>(A, flags, Abf, Yt, P, nsplit);
    } else {
        // only correct when input already bf16; in practice ws is large and haveAbf=1
        gcn_spmm<<<64 * nsplit, 256, 0, stream>>>(A, flags, (const ushort_t*)A, Yt, P, nsplit);
    }
    gcn_reduce<<<(NN * 128 / 4 + 255) / 256, 256, 0, stream>>>(P, d_deg, b, flags, d_out, nsplit);
}

// Round 4
// 411.593 us; speedup vs baseline: 1.1391x; 1.0081x over previous
//
#include <hip/hip_runtime.h>

typedef unsigned short ushort_t;
typedef unsigned int uint_t;
typedef __attribute__((ext_vector_type(8))) short bf16x8;
typedef __attribute__((ext_vector_type(8))) unsigned short us8;
typedef __attribute__((ext_vector_type(4))) float f32x4;
typedef __attribute__((ext_vector_type(4))) unsigned short us4;

#define NN 8192
#define FF 128

__device__ __forceinline__ float bf2f(ushort_t u) {
    union { unsigned u; float f; } v;
    v.u = ((unsigned)u) << 16;
    return v.f;
}

__device__ __forceinline__ ushort_t f2bf(float f) {
    union { float f; unsigned u; } v;
    v.f = f;
    unsigned r = (v.u + 0x7fffu + ((v.u >> 16) & 1u)) >> 16;  // RNE
    return (ushort_t)r;
}

// ---- Kernel 1: d[row] = rsqrt(rowsum f32)  +  Abf[row] = bf16(A[row]) ----
// Detection folded in: every block self-detects A dtype from the same 64
// sample locations (L2-hot after first blocks); block 0 also writes flags[0..2]
// for the downstream kernels.
// LLC policy: A fp32 loads NONTEMPORAL (stream); Abf stores NORMAL so the
// 128 MB bf16 copy stays Infinity-Cache-resident for spmm.
__global__ __launch_bounds__(256) void gcn_prep(const void* __restrict__ Av,
                                                const void* __restrict__ Xv,
                                                const void* __restrict__ Wv,
                                                int* __restrict__ flags,
                                                float* __restrict__ d,
                                                ushort_t* __restrict__ Abf,
                                                int haveAbf) {
    int row = blockIdx.x;
    int tid = threadIdx.x;
    __shared__ int aIsBf;
    __shared__ float red[4];

    if (tid < 64) {
        // A dtype probe: indices valid under both interpretations (<32M uints)
        uint_t u = ((const uint_t*)Av)[(size_t)tid * 499999u];
        float f = bf2f((ushort_t)(u & 0xFFFFu));
        unsigned long long m = __ballot(f >= 0.f && f < 1.f);
        if (tid == 0) aIsBf = (__popcll(m) >= 48) ? 1 : 0;
    } else if (row == 0 && tid < 128) {
        int lane = tid - 64;
        uint_t u = ((const uint_t*)Xv)[(size_t)lane * 8000u];
        float f = bf2f((ushort_t)(u & 0xFFFFu));
        float a = fabsf(f);
        unsigned long long m = __ballot(a < 8.f && (f == 0.f || a > 9.5e-7f));
        if (lane == 0) flags[1] = (__popcll(m) >= 48) ? 1 : 0;
    } else if (row == 0 && tid < 192) {
        int lane = tid - 128;
        uint_t u = ((const uint_t*)Wv)[(size_t)lane * 126u];
        float f = bf2f((ushort_t)(u & 0xFFFFu));
        float a = fabsf(f);
        unsigned long long m = __ballot(a < 8.f && (f == 0.f || a > 9.5e-7f));
        if (lane == 0) flags[2] = (__popcll(m) >= 48) ? 1 : 0;
    }
    __syncthreads();
    int isbf = aIsBf;
    if (row == 0 && tid == 0) flags[0] = isbf;

    float s = 0.f;
    if (isbf) {  // already bf16: rowsum only, spmm reads A directly (LLC keeps it)
        const bf16x8* a8 = (const bf16x8*)((const ushort_t*)Av + (size_t)row * NN);
        #pragma unroll
        for (int i = 0; i < 4; i++) {
            bf16x8 v = a8[tid + i * 256];
            #pragma unroll
            for (int j = 0; j < 8; j++) s += bf2f((ushort_t)v[j]);
        }
    } else {
        const f32x4* a4 = (const f32x4*)((const float*)Av + (size_t)row * NN);
        us4* ob = (us4*)(Abf + (size_t)row * NN);
        #pragma unroll
        for (int i = 0; i < 8; i++) {
            f32x4 v = __builtin_nontemporal_load(a4 + tid + i * 256);  // stream A past LLC
            s += v[0] + v[1] + v[2] + v[3];
            if (haveAbf) {
                us4 o;
                o[0] = f2bf(v[0]); o[1] = f2bf(v[1]); o[2] = f2bf(v[2]); o[3] = f2bf(v[3]);
                ob[tid + i * 256] = o;  // NORMAL store: keep Abf LLC-resident for spmm
            }
        }
    }
    #pragma unroll
    for (int off = 32; off > 0; off >>= 1) s += __shfl_down(s, off, 64);
    if ((tid & 63) == 0) red[tid >> 6] = s;
    __syncthreads();
    if (tid == 0) d[row] = rsqrtf(red[0] + red[1] + red[2] + red[3]);
}

// ---------------- Kernel 2: Yt[n][k] = bf16( d[k] * (X @ W)[k][n] ) ----------------
// r4: 512 threads/block (was 256). Same 256 blocks, same per-output f-loop
// order (bit-identical Yt), each thread owns 8 k-rows instead of 16.
// Occupancy 1 -> 2 waves/SIMD on this VALU-bound loop; W still staged once/block.
__global__ __launch_bounds__(512) void gcn_xw(const void* __restrict__ Xv,
                                              const void* __restrict__ Wv,
                                              const int* __restrict__ flags,
                                              const float* __restrict__ dv,
                                              ushort_t* __restrict__ Yt) {
    __shared__ ushort_t Ws[128 * 132];
    __shared__ ushort_t Xs[32 * 128];
    __shared__ float ds[32];
    int t = threadIdx.x;  // 0..511
    int k0 = blockIdx.x * 32;
    if (flags[2]) {
        const ushort_t* Wm = (const ushort_t*)Wv;
        for (int i = t; i < 128 * 128; i += 512) {
            int f = i >> 7, n = i & 127;
            Ws[n * 132 + f] = Wm[i];
        }
    } else {
        const float* Wm = (const float*)Wv;
        for (int i = t; i < 128 * 128; i += 512) {
            int f = i >> 7, n = i & 127;
            Ws[n * 132 + f] = f2bf(Wm[i]);
        }
    }
    if (flags[1]) {
        const ushort_t* X = (const ushort_t*)Xv;
        for (int i = t; i < 32 * 128; i += 512) Xs[i] = X[(size_t)k0 * FF + i];
    } else {
        const float* X = (const float*)Xv;
        for (int i = t; i < 32 * 128; i += 512) Xs[i] = f2bf(X[(size_t)k0 * FF + i]);
    }
    if (t < 32) ds[t] = dv[k0 + t];
    __syncthreads();

    int n = t & 127, kb = (t >> 7) * 8;  // 4 thread-groups x 8 k-rows
    float acc[8];
    #pragma unroll
    for (int j = 0; j < 8; j++) acc[j] = 0.f;
    for (int f = 0; f < 128; f += 4) {
        us4 wq = *(const us4*)&Ws[n * 132 + f];
        float w0 = bf2f(wq[0]), w1 = bf2f(wq[1]), w2 = bf2f(wq[2]), w3 = bf2f(wq[3]);
        #pragma unroll
        for (int j = 0; j < 8; j++) {
            us4 xq = *(const us4*)&Xs[(kb + j) * 128 + f];
            acc[j] += bf2f(xq[0]) * w0 + bf2f(xq[1]) * w1 + bf2f(xq[2]) * w2 + bf2f(xq[3]) * w3;
        }
    }
    // Each thread holds 8 CONSECUTIVE k for one row n -> one 16B us8 store
    us8 o0;
    #pragma unroll
    for (int j = 0; j < 8; j++) o0[j] = f2bf(ds[kb + j] * acc[j]);
    *(us8*)&Yt[(size_t)n * NN + (k0 + kb)] = o0;
}

// -------- Kernel 3: partial Z = Abf @ Y  (split-K, bf16 MFMA) --------
// B-tile (128n x 64k) staged in LDS once per block, XOR-swizzled 16B chunks;
// A direct global->reg; next-step A/B prefetched in regs.
// DOUBLE-BUFFERED Bs + single barrier per K-step (r3). ds_write of next tile
// lands in the idle buffer AFTER the MFMA cluster; one barrier guards the swap.
__global__ __launch_bounds__(256, 2) void gcn_spmm(const void* __restrict__ Av,
                                                   const int* __restrict__ flags,
                                                   const ushort_t* __restrict__ Abf,
                                                   const ushort_t* __restrict__ Yt,
                                                   float* __restrict__ P, int nsplit) {
    __shared__ ushort_t Bs[2][128 * 64];  // 2 x 16 KiB; chunk c of row n holds logical chunk c^(n&7)
    const int chunk = NN / nsplit;
    const int steps = chunk / 64;
    int bid = blockIdx.x;
    int rowTile = bid & 63;
    int sp = bid >> 6;
    int lane = threadIdx.x & 63;
    int w = threadIdx.x >> 6;
    int m15 = lane & 15, quad = lane >> 4;
    int row0 = rowTile * 128 + w * 32;
    const int kBeg = sp * chunk;
    const int kq = quad * 8;

    const ushort_t* Ab = flags[0] ? (const ushort_t*)Av : Abf;
    const ushort_t* pa0 = Ab + (size_t)(row0 + m15) * NN;
    const ushort_t* pa1 = Ab + (size_t)(row0 + 16 + m15) * NN;

    // B staging: wave w covers issues e = w*4+i; lane handles row rB = e*8 + (lane>>3),
    // fetching global chunk (lane&7)^(rB&7) into physical chunk lane&7.
    const ushort_t* gB[4];
    ushort_t* lB[4];  // destination in buffer 0; add buf*8192 elems for buffer 1
    #pragma unroll
    for (int i = 0; i < 4; i++) {
        int e = w * 4 + i;
        int r = e * 8 + (lane >> 3);
        int cs = (lane & 7) ^ (r & 7);
        gB[i] = Yt + (size_t)r * NN + cs * 8;
        lB[i] = &Bs[0][0] + e * 512 + lane * 8;
    }

    f32x4 acc[2][8];
    #pragma unroll
    for (int g = 0; g < 2; g++)
        #pragma unroll
        for (int c = 0; c < 8; c++) acc[g][c] = (f32x4)(0.f);

    bf16x8 a[2][2], an[2][2];
    us8 bvv[4], bvn[4];
    #pragma unroll
    for (int h = 0; h < 2; h++) {
        a[0][h] = *(const bf16x8*)(pa0 + kBeg + h * 32 + kq);
        a[1][h] = *(const bf16x8*)(pa1 + kBeg + h * 32 + kq);
    }
    #pragma unroll
    for (int i = 0; i < 4; i++) bvv[i] = *(const us8*)(gB[i] + kBeg);
    // prologue: fill buffer 0
    #pragma unroll
    for (int i = 0; i < 4; i++) *(us8*)lB[i] = bvv[i];
    __syncthreads();

    int cur = 0;
    for (int st = 0; st < steps; st++) {
        int kn = (st + 1 < steps) ? kBeg + (st + 1) * 64 : kBeg;  // wrap harmless
        #pragma unroll
        for (int i = 0; i < 4; i++) bvn[i] = *(const us8*)(gB[i] + kn);
        #pragma unroll
        for (int h = 0; h < 2; h++) {
            an[0][h] = *(const bf16x8*)(pa0 + kn + h * 32 + kq);
            an[1][h] = *(const bf16x8*)(pa1 + kn + h * 32 + kq);
        }
        const ushort_t* Bc = &Bs[0][0] + cur * 8192;
        #pragma unroll
        for (int h = 0; h < 2; h++) {
            bf16x8 bf[8];
            #pragma unroll
            for (int c = 0; c < 8; c++) {
                int n = c * 16 + m15;
                int pc = (h * 4 + quad) ^ (n & 7);
                bf[c] = *(const bf16x8*)(Bc + n * 64 + pc * 8);
            }
            #pragma unroll
            for (int c = 0; c < 8; c++) {
                acc[0][c] = __builtin_amdgcn_mfma_f32_16x16x32_bf16(a[0][h], bf[c], acc[0][c], 0, 0, 0);
                acc[1][c] = __builtin_amdgcn_mfma_f32_16x16x32_bf16(a[1][h], bf[c], acc[1][c], 0, 0, 0);
            }
        }
        // stage next tile into the idle buffer (vmcnt wait covered by the MFMAs above)
        #pragma unroll
        for (int i = 0; i < 4; i++) *(us8*)(lB[i] + (cur ^ 1) * 8192) = bvn[i];
        __syncthreads();  // single barrier: next tile ready, safe to swap
        #pragma unroll
        for (int h = 0; h < 2; h++) {
            a[0][h] = an[0][h];
            a[1][h] = an[1][h];
        }
        cur ^= 1;
    }

    // C/D layout: col = lane&15, row = quad*4 + reg  [verified m89/m91]
    float* Pp = P + (size_t)sp * (NN * 128);
    #pragma unroll
    for (int g = 0; g < 2; g++)
        #pragma unroll
        for (int c = 0; c < 8; c++)
            #pragma unroll
            for (int r = 0; r < 4; r++) {
                int row = row0 + g * 16 + quad * 4 + r;
                int n = c * 16 + m15;
                Pp[(size_t)row * 128 + n] = acc[g][c][r];
            }
}

// ---------------- Kernel 4: out = relu(d[i] * sum_s P[s] + b) ----------------
__global__ __launch_bounds__(256) void gcn_reduce(const float* __restrict__ P,
                                                  const float* __restrict__ d,
                                                  const void* __restrict__ bv,
                                                  const int* __restrict__ flags,
                                                  void* __restrict__ out, int nsplit) {
    int t = blockIdx.x * 256 + threadIdx.x;
    if (t >= NN * 128 / 4) return;
    int row = t >> 5;
    int nq = t & 31;
    f32x4 s = *(const f32x4*)(P + (size_t)t * 4);
    for (int si = 1; si < nsplit; si++)
        s += *(const f32x4*)(P + (size_t)si * (NN * 128) + (size_t)t * 4);
    float dv = d[row];
    f32x4 r;
    #pragma unroll
    for (int j = 0; j < 4; j++) {
        float bvj = flags[2] ? bf2f(((const ushort_t*)bv)[nq * 4 + j])
                             : ((const float*)bv)[nq * 4 + j];
        float x = dv * s[j] + bvj;
        r[j] = x > 0.f ? x : 0.f;
    }
    if (flags[1]) {
        us4 o;
        #pragma unroll
        for (int j = 0; j < 4; j++) o[j] = f2bf(r[j]);
        *(us4*)((ushort_t*)out + (size_t)t * 4) = o;
    } else {
        *(f32x4*)((float*)out + (size_t)t * 4) = r;
    }
}

extern "C" void kernel_launch(void* const* d_in, const int* in_sizes, int n_in,
                              void* d_out, int out_size, void* d_ws, size_t ws_size,
                              hipStream_t stream) {
    const void* A = d_in[0];  // [8192][8192]
    const void* X = d_in[1];  // [8192][128]
    const void* W = d_in[2];  // [128][128]
    const void* b = d_in[3];  // [128]

    char* wsb = (char*)d_ws;
    int* flags = (int*)wsb;                                   // 1 KB
    float* d_deg = (float*)(wsb + 1024);                      // 32 KB
    ushort_t* Yt = (ushort_t*)(wsb + 1024 + 32768);           // 2 MB
    const size_t pOff = 1024 + 32768 + 2097152;               // 2130944
    float* P = (float*)(wsb + pOff);                          // nsplit * 4 MB

    int nsplit = 1;
    if (pOff + 8ull * 4194304 <= ws_size) nsplit = 8;
    else if (pOff + 4ull * 4194304 <= ws_size) nsplit = 4;
    else if (pOff + 2ull * 4194304 <= ws_size) nsplit = 2;

    const size_t abfOff = pOff + (size_t)nsplit * 4194304;
    int haveAbf = (abfOff + 134217728ull <= ws_size) ? 1 : 0;  // 128 MiB bf16 copy of A
    ushort_t* Abf = (ushort_t*)(wsb + abfOff);

    gcn_prep<<<NN, 256, 0, stream>>>(A, X, W, flags, d_deg, Abf, haveAbf);
    gcn_xw<<<NN / 32, 512, 0, stream>>>(X, W, flags, d_deg, Yt);
    if (haveAbf) {
        gcn_spmm<<<64 * nsplit, 256, 0, stream>>>(A, flags, Abf, Yt, P, nsplit);
    } else {
        // only correct when input already bf16; in practice ws is large and haveAbf=1
        gcn_spmm<<<64 * nsplit, 256, 0, stream>>>(A, flags, (const ushort_t*)A, Yt, P, nsplit);
    }
    gcn_reduce<<<(NN * 128 / 4 + 255) / 256, 256, 0, stream>>>(P, d_deg, b, flags, d_out, nsplit);
}